// Round 4
// baseline (1014.353 us; speedup 1.0000x reference)
//
#include <hip/hip_runtime.h>
#include <cstddef>

static constexpr int N_NODES = 50000;
static constexpr int N_EDGES = 400000;
static constexpr int D = 256;
static constexpr int R = 2;
static constexpr int M_PAD = 50048;   // 391 * 128 (MFMA grid pad)
static constexpr int CAP = 32;        // bucket capacity; max seg degree ~20 (Poisson(4))
static constexpr int NSEG = N_NODES * R;

typedef _Float16 f16x8 __attribute__((ext_vector_type(8)));
typedef float f32x4 __attribute__((ext_vector_type(4)));

__device__ __forceinline__ unsigned short f2h(float f) {
    _Float16 h = (_Float16)f;
    return *(unsigned short*)&h;
}

#define GLOAD16(g, l)                                                          \
    __builtin_amdgcn_global_load_lds(                                          \
        (const __attribute__((address_space(1))) void*)(g),                    \
        (__attribute__((address_space(3))) void*)(l), 16, 0, 0)

// ===========================================================================
// fp32 multi-slab vector GEMM — VERIFIED in round 1. X-path must stay fp32:
// the MoE top-1 gate is discontinuous in X3; bf16 X-path noise flips argmax
// for ~50 near-tie nodes (round-2 failure). Do not lower precision here
// without split-precision accumulation (>= 2^-22 rel).
// ===========================================================================
struct GemmArgs {
    const float* xs[4];
    const float* ws[4];
    int ks[4];
    int strides[4];
    int nslab;
    int M;
    const float* bias;
    float* out;
};

template<int ACT>
__global__ __launch_bounds__(256)
void gemm_f32(GemmArgs a) {
    __shared__ float As[16][68];
    __shared__ float Bs[16][64];
    const int tid  = threadIdx.x;
    const int row0 = blockIdx.x * 64;
    const int n0   = blockIdx.y * 64;
    const int tx   = tid & 15, ty = tid >> 4;
    const int arow = tid >> 2;
    const int aq   = (tid & 3) << 2;
    const int brow = tid >> 4;
    const int bcol = (tid & 15) << 2;

    float acc[4][4] = {};

    for (int s = 0; s < a.nslab; ++s) {
        const float* __restrict__ xp = a.xs[s];
        const float* __restrict__ wp = a.ws[s];
        const int K = a.ks[s];
        const int stride = a.strides[s];
        for (int k0 = 0; k0 < K; k0 += 16) {
            float4 av = make_float4(0.f, 0.f, 0.f, 0.f);
            const int grow = row0 + arow;
            if (grow < a.M)
                av = *(const float4*)(xp + (size_t)grow * stride + (k0 + aq));
            const float4 bv = *(const float4*)(wp + (size_t)(k0 + brow) * D + (n0 + bcol));
            __syncthreads();
            As[aq + 0][arow] = av.x;
            As[aq + 1][arow] = av.y;
            As[aq + 2][arow] = av.z;
            As[aq + 3][arow] = av.w;
            *(float4*)&Bs[brow][bcol] = bv;
            __syncthreads();
            #pragma unroll
            for (int kk = 0; kk < 16; ++kk) {
                const float4 af = *(const float4*)&As[kk][ty << 2];
                const float4 bf = *(const float4*)&Bs[kk][tx << 2];
                const float aa[4] = {af.x, af.y, af.z, af.w};
                const float bb[4] = {bf.x, bf.y, bf.z, bf.w};
                #pragma unroll
                for (int i = 0; i < 4; ++i)
                    #pragma unroll
                    for (int j = 0; j < 4; ++j)
                        acc[i][j] = fmaf(aa[i], bb[j], acc[i][j]);
            }
        }
    }

    #pragma unroll
    for (int i = 0; i < 4; ++i) {
        const int grow = row0 + (ty << 2) + i;
        if (grow >= a.M) continue;
        float4 o;
        float* op = (float*)&o;
        #pragma unroll
        for (int j = 0; j < 4; ++j) {
            const int col = n0 + (tx << 2) + j;
            float v = acc[i][j] + a.bias[col];
            if (ACT == 1) {
                const float scale = 1.0507009873554804934f;
                const float alpha = 1.6732632423543772848f;
                v = (v > 0.f) ? scale * v : scale * alpha * (expf(v) - 1.f);
            }
            op[j] = v;
        }
        *(float4*)(a.out + (size_t)grow * D + n0 + (tx << 2)) = o;
    }
}

// ===========================================================================
// f16 MFMA GEMM (MoE only this round — continuous error path).
// 128x128 tile, BK=64, 4 waves, 4x4 frags of mfma_f32_16x16x32_f16.
// LDS XOR granule swizzle (T2, rule #21): global source pre-swizzled so the
// linear global_load_lds dest + XOR'd ds_read_b128 are a consistent involution.
// ===========================================================================
struct MSlab { const unsigned short* x; const unsigned short* w; int xstr, wstr, klen; };
struct MArgs {
    MSlab sl[4];
    int nslab, M;
    const float* bias;
    const int* sel;
    int expert;
    void* out;
    int ldc;
};

template<int ACT, bool MASK, bool SELB, bool OUTF16>
__global__ __launch_bounds__(256)
void mgemm(MArgs a) {
    __shared__ unsigned short As[128 * 64];
    __shared__ unsigned short Bs[128 * 64];
    const int tid  = threadIdx.x;
    const int wave = tid >> 6, lane = tid & 63;
    const int wm = wave >> 1, wn = wave & 1;
    const int row0 = blockIdx.x * 128;
    const int n0   = blockIdx.y * 128;

    const int srow = lane >> 3;                               // 0..7
    const int scol = ((lane & 7) ^ (lane >> 3)) << 3;         // swizzled src granule

    f32x4 acc[4][4] = {};

    for (int s = 0; s < a.nslab; ++s) {
        const unsigned short* xp = a.sl[s].x;
        const unsigned short* wp = a.sl[s].w;
        const int xstr = a.sl[s].xstr, wstr = a.sl[s].wstr, klen = a.sl[s].klen;
        for (int k0 = 0; k0 < klen; k0 += 64) {
            __syncthreads();
            #pragma unroll
            for (int i = 0; i < 4; ++i) {
                const int r = wave * 32 + i * 8;
                GLOAD16(xp + (size_t)(row0 + r + srow) * xstr + k0 + scol, &As[r * 64]);
            }
            #pragma unroll
            for (int i = 0; i < 4; ++i) {
                const int r = wave * 32 + i * 8;
                GLOAD16(wp + (size_t)(n0 + r + srow) * wstr + k0 + scol, &Bs[r * 64]);
            }
            __syncthreads();

            #pragma unroll
            for (int kk = 0; kk < 2; ++kk) {
                const int gk = kk * 4 + (lane >> 4);          // 16B k-granule 0..7
                f16x8 af[4], bfr[4];
                #pragma unroll
                for (int m = 0; m < 4; ++m) {
                    const int rr = wm * 64 + m * 16 + (lane & 15);
                    af[m] = *(const f16x8*)&As[rr * 64 + ((gk ^ (rr & 7)) << 3)];
                }
                #pragma unroll
                for (int n = 0; n < 4; ++n) {
                    const int rr = wn * 64 + n * 16 + (lane & 15);
                    bfr[n] = *(const f16x8*)&Bs[rr * 64 + ((gk ^ (rr & 7)) << 3)];
                }
                #pragma unroll
                for (int m = 0; m < 4; ++m)
                    #pragma unroll
                    for (int n = 0; n < 4; ++n)
                        acc[m][n] = __builtin_amdgcn_mfma_f32_16x16x32_f16(
                            af[m], bfr[n], acc[m][n], 0, 0, 0);
            }
        }
    }

    // C/D: col = lane&15, row = (lane>>4)*4 + reg   [m89-verified layout]
    const int erow = (lane >> 4) * 4;
    const int ecol = lane & 15;
    #pragma unroll
    for (int m = 0; m < 4; ++m) {
        #pragma unroll
        for (int r = 0; r < 4; ++r) {
            const int grow = row0 + wm * 64 + m * 16 + erow + r;
            if (grow >= a.M) continue;
            int sv = 0;
            if (MASK || SELB) sv = a.sel[grow];
            #pragma unroll
            for (int n = 0; n < 4; ++n) {
                const int gcol = n0 + wn * 64 + n * 16 + ecol;
                const float b = SELB ? a.bias[sv * 256 + gcol] : a.bias[gcol];
                float v = acc[m][n][r] + b;
                if (ACT == 2) v = (v >= 0.f) ? v : 0.01f * v;
                if (MASK && sv != a.expert) v = 0.f;
                if (OUTF16)
                    ((unsigned short*)a.out)[(size_t)grow * a.ldc + gcol] = f2h(v);
                else
                    ((float*)a.out)[(size_t)grow * a.ldc + gcol] = v;
            }
        }
    }
}

// ===========================================================================
// bucket-CSR build (once; edges identical for both RGCN layers)
// ===========================================================================
__global__ __launch_bounds__(256)
void csr_build(const int* __restrict__ ei, const int* __restrict__ et,
               int* cnt, int* slots) {
    const int e = blockIdx.x * 256 + threadIdx.x;
    if (e >= N_EDGES) return;
    const int src = ei[e];
    const int dst = ei[N_EDGES + e];
    const int seg = dst * R + et[e];
    const int slot = atomicAdd(&cnt[seg], 1);
    if (slot < CAP) slots[(size_t)seg * CAP + slot] = src;
}

// one wave per segment: mean of gathered X rows -> Ab[(n-local)*512 + r*256 + d]
__global__ __launch_bounds__(256)
void aggregate(const float* __restrict__ X, const int* __restrict__ cnt,
               const int* __restrict__ slots, float* __restrict__ Ab,
               int seg0, int nseg) {
    const int w = blockIdx.x * 4 + (threadIdx.x >> 6);
    if (w >= nseg) return;
    const int lane = threadIdx.x & 63;
    const int s = seg0 + w;
    const int m = min(cnt[s], CAP);
    const int* sl = slots + (size_t)s * CAP;
    float4 acc = make_float4(0.f, 0.f, 0.f, 0.f);
    for (int i = 0; i < m; ++i) {
        const float4 v = *(const float4*)(X + (size_t)sl[i] * 256 + lane * 4);
        acc.x += v.x; acc.y += v.y; acc.z += v.z; acc.w += v.w;
    }
    const float inv = (m > 0) ? 1.0f / (float)m : 0.0f;
    acc.x *= inv; acc.y *= inv; acc.z *= inv; acc.w *= inv;
    *(float4*)(Ab + (size_t)(w >> 1) * 512 + (w & 1) * 256 + lane * 4) = acc;
}

// gate: sel[n] = argmax(X3_f32[n] @ w_gate)  (NE=2, tie -> 0) — round-1 verified
__global__ __launch_bounds__(256)
void gate_kernel(const float* __restrict__ x, const float* __restrict__ wg,
                 int* sel, int M) {
    __shared__ float wl[2 * D];
    const int tid = threadIdx.x;
    wl[tid] = wg[tid];
    wl[tid + 256] = wg[tid + 256];
    __syncthreads();
    const int wave = tid >> 6, lane = tid & 63;
    const int row = blockIdx.x * 4 + wave;
    if (row >= M) return;
    const float* xr = x + (size_t)row * D;
    float z0 = 0.f, z1 = 0.f;
    #pragma unroll
    for (int p = 0; p < 4; ++p) {
        const int k = lane + (p << 6);
        const float xv = xr[k];
        z0 = fmaf(xv, wl[2 * k], z0);
        z1 = fmaf(xv, wl[2 * k + 1], z1);
    }
    #pragma unroll
    for (int off = 32; off; off >>= 1) {
        z0 += __shfl_down(z0, off, 64);
        z1 += __shfl_down(z1, off, 64);
    }
    if (lane == 0) sel[row] = (z1 > z0) ? 1 : 0;
}

// MoE weight transpose+f16: dst[n*stride + koff + k] = f16(src[k*256 + n])
struct WJob4 { const float* src[4]; unsigned short* dst[4]; int stride[4]; };
__global__ __launch_bounds__(256)
void wconv_moe(WJob4 j) {
    const int job = blockIdx.y;
    const int i = blockIdx.x * 256 + threadIdx.x;   // 256*256
    const int k = i >> 8, n = i & 255;
    j.dst[job][(size_t)n * j.stride[job] + k] = f2h(j.src[job][i]);
}

// X3 f32 -> f16 (covers M_PAD rows; pad rows hold poison -> tiny denormal -> -0)
__global__ __launch_bounds__(256)
void x3conv(const float* __restrict__ X3, unsigned short* __restrict__ X3h) {
    const int i = blockIdx.x * 256 + threadIdx.x;   // float4 units
    const float4 v = ((const float4*)X3)[i];
    ushort4 o = make_ushort4(f2h(v.x), f2h(v.y), f2h(v.z), f2h(v.w));
    ((ushort4*)X3h)[i] = o;
}

// ===========================================================================
extern "C" void kernel_launch(void* const* d_in, const int* in_sizes, int n_in,
                              void* d_out, int out_size, void* d_ws, size_t ws_size,
                              hipStream_t stream) {
    const float* des    = (const float*)d_in[0];
    const float* twt    = (const float*)d_in[1];
    const float* nump   = (const float*)d_in[2];
    const float* catp   = (const float*)d_in[3];
    const int*   ei     = (const int*)d_in[4];
    const int*   et     = (const int*)d_in[5];
    const float* W_in   = (const float*)d_in[6];
    const float* b_in   = (const float*)d_in[7];
    const float* W_rel  = (const float*)d_in[8];
    const float* W_root = (const float*)d_in[9];
    const float* b_rg   = (const float*)d_in[10];
    const float* w_gate = (const float*)d_in[11];
    const float* We1    = (const float*)d_in[12];
    const float* be1    = (const float*)d_in[13];
    const float* We2    = (const float*)d_in[14];
    const float* be2    = (const float*)d_in[15];

    // ---- workspace layout (~193 MB) ----
    char* ws = (char*)d_ws;
    size_t off = 0;
    float* X1 = (float*)(ws + off); off += (size_t)M_PAD * 256 * 4;   // 51.25 MB (X3 aliases)
    float* X3 = X1;
    float* X2 = (float*)(ws + off); off += (size_t)M_PAD * 256 * 4;   // 51.25 MB
    // regionA: Ab (layers) then {X3h | H} (MoE) — disjoint lifetimes
    char* regionA = ws + off; off += (size_t)M_PAD * 512 * 2 + (size_t)M_PAD * 256 * 2; // 76.9 MB
    float* Ab = (float*)regionA;                                       // 25024*512*4 = 51.25 MB used
    unsigned short* X3h = (unsigned short*)regionA;                    // M_PAD*256*2 = 25.62 MB
    unsigned short* H   = (unsigned short*)(regionA + (size_t)M_PAD * 256 * 2); // M_PAD*512*2
    int* cnt   = (int*)(ws + off); off += (size_t)NSEG * 4;
    int* sel   = (int*)(ws + off); off += (size_t)N_NODES * 4;
    int* slots = (int*)(ws + off); off += (size_t)NSEG * CAP * 4;      // 12.8 MB
    unsigned short* Wt_e1h0 = (unsigned short*)(ws + off); off += 256 * 256 * 2;
    unsigned short* Wt_e1h1 = (unsigned short*)(ws + off); off += 256 * 256 * 2;
    unsigned short* Wt_e2h  = (unsigned short*)(ws + off); off += 256 * 512 * 2;

    const dim3 blk(256);

    // ---- CSR build (once) + MoE weight conv ----
    hipMemsetAsync(cnt, 0, (size_t)NSEG * 4, stream);
    csr_build<<<(N_EDGES + 255) / 256, blk, 0, stream>>>(ei, et, cnt, slots);
    {
        WJob4 j;
        j.src[0] = We1;           j.dst[0] = Wt_e1h0;      j.stride[0] = 256;
        j.src[1] = We1 + D * D;   j.dst[1] = Wt_e1h1;      j.stride[1] = 256;
        j.src[2] = We2;           j.dst[2] = Wt_e2h;       j.stride[2] = 512;
        j.src[3] = We2 + D * D;   j.dst[3] = Wt_e2h + 256; j.stride[3] = 512;
        wconv_moe<<<dim3(256, 4), blk, 0, stream>>>(j);
    }

    // ---- stage 1: X1 = selu(concat @ W_in + b_in)  [fp32, full M] ----
    {
        GemmArgs g{};
        g.xs[0] = des;  g.ws[0] = W_in;            g.ks[0] = 128; g.strides[0] = 128;
        g.xs[1] = twt;  g.ws[1] = W_in + 128 * D;  g.ks[1] = 64;  g.strides[1] = 64;
        g.xs[2] = nump; g.ws[2] = W_in + 192 * D;  g.ks[2] = 32;  g.strides[2] = 32;
        g.xs[3] = catp; g.ws[3] = W_in + 224 * D;  g.ks[3] = 32;  g.strides[3] = 32;
        g.nslab = 4; g.M = N_NODES; g.bias = b_in; g.out = X1;
        hipLaunchKernelGGL((gemm_f32<1>), dim3(782, 4), blk, 0, stream, g);
    }

    // ---- RGCN layers, 2 node-chunks each (Ab reused; CSR reused) ----
    const float* rg_in[2]  = {X1, X2};
    float*       rg_out[2] = {X2, X3};
    const int c0s[2] = {0, 25000};
    const int c1s[2] = {25000, 50000};
    for (int layer = 0; layer < 2; ++layer) {
        for (int c = 0; c < 2; ++c) {
            const int c0 = c0s[c], c1 = c1s[c];
            const int mrows = c1 - c0;
            const int nseg = mrows * R;
            aggregate<<<(nseg + 3) / 4, blk, 0, stream>>>(
                rg_in[layer], cnt, slots, Ab, c0 * R, nseg);
            GemmArgs g{};
            g.xs[0] = rg_in[layer] + (size_t)c0 * 256; g.ws[0] = W_root;      g.ks[0] = D; g.strides[0] = D;
            g.xs[1] = Ab;                              g.ws[1] = W_rel;       g.ks[1] = D; g.strides[1] = 512;
            g.xs[2] = Ab + 256;                        g.ws[2] = W_rel + D*D; g.ks[2] = D; g.strides[2] = 512;
            g.nslab = 3; g.M = mrows; g.bias = b_rg;
            g.out = rg_out[layer] + (size_t)c0 * 256;
            hipLaunchKernelGGL((gemm_f32<0>), dim3((mrows + 63) / 64, 4), blk, 0, stream, g);
        }
    }

    // ---- MoE top-1 ----
    gate_kernel<<<(N_NODES + 3) / 4, blk, 0, stream>>>(X3, w_gate, sel, N_NODES);
    x3conv<<<M_PAD / 4, blk, 0, stream>>>(X3, X3h);

    for (int e = 0; e < 2; ++e) {
        MArgs g{};
        g.sl[0] = {X3h, (e == 0) ? Wt_e1h0 : Wt_e1h1, 256, 256, 256};
        g.nslab = 1; g.M = N_NODES;
        g.bias = be1 + e * 256; g.sel = sel; g.expert = e;
        g.out = H + e * 256; g.ldc = 512;
        hipLaunchKernelGGL((mgemm<2, true, false, true>), dim3(M_PAD / 128, 2), blk, 0, stream, g);
    }
    {
        MArgs g{};
        g.sl[0] = {H, Wt_e2h, 512, 512, 512};
        g.nslab = 1; g.M = N_NODES;
        g.bias = be2; g.sel = sel;
        g.out = d_out; g.ldc = 256;
        hipLaunchKernelGGL((mgemm<0, false, true, false>), dim3(M_PAD / 128, 2), blk, 0, stream, g);
    }
}